// Round 1
// baseline (975.681 us; speedup 1.0000x reference)
//
#include <hip/hip_runtime.h>
#include <hip/hip_bf16.h>
#include <math.h>

#define T_TOK 8192
#define E_EXP 8
#define D_DIM 1024
#define H_DIM 4096
#define K_CAP 1024

typedef __attribute__((ext_vector_type(8))) short short8;
typedef __attribute__((ext_vector_type(4))) float floatx4;

static __device__ __forceinline__ unsigned int f2bf_u(float f) {
  union { float f; unsigned int u; } v; v.f = f;
  unsigned int r = v.u + 0x7FFF + ((v.u >> 16) & 1);
  return r >> 16;
}

// ---------------- zero output ----------------
__global__ __launch_bounds__(256) void zero_kernel(float* __restrict__ p, int n4) {
  int i = blockIdx.x * 256 + threadIdx.x;
  if (i < n4) ((floatx4*)p)[i] = (floatx4)0.0f;
}

// ---------------- router: fp64 logits + softmax, build sort keys ----------------
__global__ __launch_bounds__(256)
void router_kernel(const float* __restrict__ x, const float* __restrict__ rw,
                   float* __restrict__ logits_out, float* __restrict__ probs_ws,
                   unsigned long long* __restrict__ keys_ws) {
  int t = blockIdx.x;
  int tid = threadIdx.x;
  int lane = tid & 63, wid = tid >> 6;
  __shared__ float xs[D_DIM];
  __shared__ double dred[4 * E_EXP];
  __shared__ double dlog[E_EXP];
  for (int i = tid; i < D_DIM; i += 256) xs[i] = x[(size_t)t * D_DIM + i];
  __syncthreads();
#pragma unroll
  for (int e = 0; e < E_EXP; e++) {
    double s = 0.0;
#pragma unroll
    for (int i = 0; i < 4; i++) {
      int d = tid + i * 256;
      s += (double)xs[d] * (double)rw[e * D_DIM + d];
    }
#pragma unroll
    for (int off = 32; off > 0; off >>= 1) s += __shfl_down(s, off, 64);
    if (lane == 0) dred[wid * E_EXP + e] = s;
  }
  __syncthreads();
  if (tid < E_EXP) {
    double s = dred[tid] + dred[E_EXP + tid] + dred[2 * E_EXP + tid] + dred[3 * E_EXP + tid];
    dlog[tid] = s;
    logits_out[(size_t)t * E_EXP + tid] = (float)s;
  }
  __syncthreads();
  if (tid == 0) {
    double m = dlog[0];
#pragma unroll
    for (int e = 1; e < E_EXP; e++) m = dlog[e] > m ? dlog[e] : m;
    double ex[E_EXP], Z = 0.0;
#pragma unroll
    for (int e = 0; e < E_EXP; e++) { ex[e] = exp(dlog[e] - m); Z += ex[e]; }
#pragma unroll
    for (int e = 0; e < E_EXP; e++) {
      double p = ex[e] / Z;
      probs_ws[e * T_TOK + t] = (float)p;
      unsigned long long b = (unsigned long long)__double_as_longlong(p);
      // descending by prob, ties -> smaller token index first (stable top_k)
      keys_ws[e * T_TOK + t] = (b & ~8191ULL) | (unsigned long long)(8191 - t);
    }
  }
}

// ---------------- exact top-k by rank counting (keys are unique) ----------------
__global__ __launch_bounds__(256)
void topk_kernel(const unsigned long long* __restrict__ keys_ws,
                 const float* __restrict__ probs_ws,
                 int* __restrict__ sel_ws, float* __restrict__ wt_ws,
                 float* __restrict__ selout) {
  int e = blockIdx.x >> 3, seg = blockIdx.x & 7;
  int tid = threadIdx.x;
  const unsigned long long* keys = keys_ws + (size_t)e * T_TOK;
  __shared__ unsigned long long kbuf[4096];
  unsigned long long own[4];
  int rank[4];
  int tbase = seg * 1024 + tid * 4;
#pragma unroll
  for (int c = 0; c < 4; c++) { own[c] = keys[tbase + c]; rank[c] = 0; }
  for (int pass = 0; pass < 2; pass++) {
    __syncthreads();
    for (int j = tid; j < 4096; j += 256) kbuf[j] = keys[pass * 4096 + j];
    __syncthreads();
    for (int j = 0; j < 4096; j++) {
      unsigned long long k = kbuf[j];  // LDS broadcast (all lanes same addr)
      rank[0] += (k > own[0]); rank[1] += (k > own[1]);
      rank[2] += (k > own[2]); rank[3] += (k > own[3]);
    }
  }
#pragma unroll
  for (int c = 0; c < 4; c++) {
    if (rank[c] < K_CAP) {
      int t = tbase + c;
      sel_ws[e * K_CAP + rank[c]] = t;
      wt_ws[e * K_CAP + rank[c]] = probs_ws[e * T_TOK + t];
      selout[e * K_CAP + rank[c]] = (float)t;  // harness reads outputs as float
    }
  }
}

// ---------------- tiled bf16 MFMA GEMM, templated epilogue ----------------
// C[M,N] = A[M,K] * B[K,N]; A gathered rows (MODE1: fp32 x rows via sel; MODE2: bf16 H rows)
// B is fp32 [K,N], converted+transposed into LDS.
#define BM 128
#define BN 128
#define BKK 32
#define LDA 40  // 32 + 8 pad (shorts) -> 80B row stride

template <int MODE, int KDIM, int NDIM>
__global__ __launch_bounds__(256, 2)
void gemm_kernel(const float* __restrict__ xsrc,
                 const unsigned short* __restrict__ hsrc,
                 const float* __restrict__ w,
                 const float* __restrict__ bias,
                 const int* __restrict__ sel,
                 const float* __restrict__ wt,
                 unsigned short* __restrict__ hout,
                 float* __restrict__ results) {
  int e = blockIdx.z;
  int n0 = blockIdx.x * BN;
  int m0 = blockIdx.y * BM;
  int tid = threadIdx.x;
  int lane = tid & 63, wid = tid >> 6;
  int wave_m = wid >> 1, wave_n = wid & 1;
  __shared__ unsigned short Asm_[BM * LDA];
  __shared__ unsigned short Bsm[BN * LDA];

  const float* wbase = w + (size_t)e * KDIM * NDIM;

  int r = tid >> 1;              // A staging: row within tile
  int halfk = (tid & 1) * 16;    // which half of the BK=32 slice
  const float* arow_f = nullptr;
  const unsigned short* arow_h = nullptr;
  if (MODE == 1) {
    int tok = sel[e * K_CAP + m0 + r];
    arow_f = xsrc + (size_t)tok * D_DIM;
  } else {
    arow_h = hsrc + ((size_t)e * K_CAP + m0 + r) * H_DIM;
  }
  int p2 = tid >> 4;  // 0..15 -> k-row pair 2p2,2p2+1
  int g = tid & 15;   // n group of 8

  floatx4 acc[4][4];
#pragma unroll
  for (int i = 0; i < 4; i++)
#pragma unroll
    for (int j = 0; j < 4; j++) acc[i][j] = (floatx4)0.0f;

  int lm = lane & 15;
  int q8 = (lane >> 4) * 8;

  for (int k0 = 0; k0 < KDIM; k0 += BKK) {
    // ---- stage A (128 x 32 bf16) ----
    if (MODE == 1) {
#pragma unroll
      for (int c = 0; c < 4; c++) {
        floatx4 f = *(const floatx4*)(arow_f + k0 + halfk + c * 4);
        unsigned int p01 = f2bf_u(f.x) | (f2bf_u(f.y) << 16);
        unsigned int p23 = f2bf_u(f.z) | (f2bf_u(f.w) << 16);
        unsigned int* dst = (unsigned int*)&Asm_[r * LDA + halfk + c * 4];
        dst[0] = p01; dst[1] = p23;
      }
    } else {
#pragma unroll
      for (int c = 0; c < 2; c++) {
        uint4 ud = *(const uint4*)(arow_h + k0 + halfk + c * 8);
        *(uint4*)&Asm_[r * LDA + halfk + c * 8] = ud;
      }
    }
    // ---- stage B transposed: Bsm[n][k] (128 x 32 bf16) ----
    {
      const float* b0 = wbase + (size_t)(k0 + 2 * p2) * NDIM + n0 + g * 8;
      const float* b1 = b0 + NDIM;
#pragma unroll
      for (int c = 0; c < 2; c++) {
        floatx4 fa = *(const floatx4*)(b0 + c * 4);
        floatx4 fb = *(const floatx4*)(b1 + c * 4);
#pragma unroll
        for (int i = 0; i < 4; i++) {
          unsigned int pk = f2bf_u(fa[i]) | (f2bf_u(fb[i]) << 16);
          int n = g * 8 + c * 4 + i;
          *(unsigned int*)&Bsm[n * LDA + 2 * p2] = pk;
        }
      }
    }
    __syncthreads();
    short8 av[4], bv[4];
#pragma unroll
    for (int i = 0; i < 4; i++) {
      av[i] = *(const short8*)&Asm_[(wave_m * 64 + i * 16 + lm) * LDA + q8];
      bv[i] = *(const short8*)&Bsm[(wave_n * 64 + i * 16 + lm) * LDA + q8];
    }
#pragma unroll
    for (int mi = 0; mi < 4; mi++)
#pragma unroll
      for (int ni = 0; ni < 4; ni++)
        acc[mi][ni] = __builtin_amdgcn_mfma_f32_16x16x32_bf16(av[mi], bv[ni], acc[mi][ni], 0, 0, 0);
    __syncthreads();
  }

  // ---- epilogue ----
  int quad = lane >> 4;
#pragma unroll
  for (int mi = 0; mi < 4; mi++) {
#pragma unroll
    for (int rg = 0; rg < 4; rg++) {
      int m_l = wave_m * 64 + mi * 16 + quad * 4 + rg;
      int m_g = m0 + m_l;
      if (MODE == 1) {
#pragma unroll
        for (int ni = 0; ni < 4; ni++) {
          int n_l = wave_n * 64 + ni * 16 + lm;
          float v = acc[mi][ni][rg] + bias[e * NDIM + n0 + n_l];
          float gl = 0.5f * v * (1.0f + erff(v * 0.70710678118f));  // exact GELU
          hout[((size_t)e * K_CAP + m_g) * H_DIM + n0 + n_l] = (unsigned short)f2bf_u(gl);
        }
      } else {
        int tok = sel[e * K_CAP + m_g];
        float wgt = wt[e * K_CAP + m_g];
#pragma unroll
        for (int ni = 0; ni < 4; ni++) {
          int n_l = wave_n * 64 + ni * 16 + lm;
          float v = (acc[mi][ni][rg] + bias[e * NDIM + n0 + n_l]) * wgt;
          atomicAdd(&results[(size_t)tok * D_DIM + n0 + n_l], v);
        }
      }
    }
  }
}

extern "C" void kernel_launch(void* const* d_in, const int* in_sizes, int n_in,
                              void* d_out, int out_size, void* d_ws, size_t ws_size,
                              hipStream_t stream) {
  const float* x  = (const float*)d_in[0];
  const float* rw = (const float*)d_in[1];
  const float* w1 = (const float*)d_in[2];
  const float* b1 = (const float*)d_in[3];
  const float* w2 = (const float*)d_in[4];
  const float* b2 = (const float*)d_in[5];

  float* out_res = (float*)d_out;                      // [8192][1024] fp32
  float* out_log = out_res + (size_t)T_TOK * D_DIM;    // [8192][8] fp32
  float* out_sel = out_log + (size_t)T_TOK * E_EXP;    // [8][1024] (token ids as float)

  char* ws = (char*)d_ws;
  float* probs_ws = (float*)ws;                                  // 8*8192 f32   = 256KB
  unsigned long long* keys_ws = (unsigned long long*)(ws + 262144);  // 8*8192 u64 = 512KB
  int* sel_ws = (int*)(ws + 786432);                             // 8*1024 i32  = 32KB
  float* wt_ws = (float*)(ws + 819200);                          // 8*1024 f32  = 32KB
  unsigned short* h_ws = (unsigned short*)(ws + 851968);         // 8*1024*4096 bf16 = 64MB

  // zero the scatter-add destination (results region only)
  zero_kernel<<<(T_TOK * D_DIM / 4 + 255) / 256, 256, 0, stream>>>(out_res, T_TOK * D_DIM / 4);

  router_kernel<<<T_TOK, 256, 0, stream>>>(x, rw, out_log, probs_ws, keys_ws);

  topk_kernel<<<64, 256, 0, stream>>>(keys_ws, probs_ws, sel_ws, wt_ws, out_sel);

  // H = gelu(Xg @ W1 + b1)  -> bf16 ws
  gemm_kernel<1, 1024, 4096><<<dim3(32, 8, 8), 256, 0, stream>>>(
      x, nullptr, w1, b1, sel_ws, wt_ws, h_ws, nullptr);

  // results += weight * (H @ W2 + b2), scattered by token
  gemm_kernel<2, 4096, 1024><<<dim3(8, 8, 8), 256, 0, stream>>>(
      nullptr, h_ws, w2, b2, sel_ws, wt_ws, nullptr, out_res);
}

// Round 2
// 714.938 us; speedup vs baseline: 1.3647x; 1.3647x over previous
//
#include <hip/hip_runtime.h>
#include <hip/hip_bf16.h>
#include <math.h>

#define T_TOK 8192
#define E_EXP 8
#define D_DIM 1024
#define H_DIM 4096
#define K_CAP 1024

typedef __attribute__((ext_vector_type(8))) short short8;
typedef __attribute__((ext_vector_type(4))) float floatx4;

typedef __attribute__((address_space(3))) unsigned int lds_u32_t;
typedef __attribute__((address_space(1))) unsigned int gbl_u32_t;
#define ASYNC_CP16(gptr, lptr) \
  __builtin_amdgcn_global_load_lds((gbl_u32_t*)(gptr), (lds_u32_t*)(lptr), 16, 0, 0)

static __device__ __forceinline__ unsigned int f2bf_u(float f) {
  union { float f; unsigned int u; } v; v.f = f;
  unsigned int r = v.u + 0x7FFF + ((v.u >> 16) & 1);
  return r >> 16;
}

// ---------------- zero output ----------------
__global__ __launch_bounds__(256) void zero_kernel(float* __restrict__ p, int n4) {
  int i = blockIdx.x * 256 + threadIdx.x;
  if (i < n4) ((floatx4*)p)[i] = (floatx4)0.0f;
}

// ---------------- fp32 -> bf16 convert (x) ----------------
__global__ __launch_bounds__(256)
void convert_kernel(const float* __restrict__ x, unsigned short* __restrict__ xb, int n4) {
  int i = blockIdx.x * 256 + threadIdx.x;
  if (i < n4) {
    float4 v = ((const float4*)x)[i];
    uint2 u;
    u.x = f2bf_u(v.x) | (f2bf_u(v.y) << 16);
    u.y = f2bf_u(v.z) | (f2bf_u(v.w) << 16);
    ((uint2*)xb)[i] = u;
  }
}

// ---------------- transpose + convert: W [E][KD][ND] f32 -> WT [E][ND][KD] bf16 ----
template <int KD, int ND>
__global__ __launch_bounds__(256)
void transpose_kernel(const float* __restrict__ w, unsigned short* __restrict__ wt) {
  int e = blockIdx.z;
  int n0 = blockIdx.x * 32, k0 = blockIdx.y * 32;
  __shared__ float ts[32][33];
  int tid = threadIdx.x;
  int r = tid >> 3, c4 = (tid & 7) * 4;
  const float* src = w + ((size_t)e * KD + k0 + r) * ND + n0 + c4;
  float4 v = *(const float4*)src;
  ts[r][c4 + 0] = v.x; ts[r][c4 + 1] = v.y; ts[r][c4 + 2] = v.z; ts[r][c4 + 3] = v.w;
  __syncthreads();
  unsigned int p0 = f2bf_u(ts[c4 + 0][r]) | (f2bf_u(ts[c4 + 1][r]) << 16);
  unsigned int p1 = f2bf_u(ts[c4 + 2][r]) | (f2bf_u(ts[c4 + 3][r]) << 16);
  unsigned short* dst = wt + ((size_t)e * ND + n0 + r) * KD + k0 + c4;
  uint2 u; u.x = p0; u.y = p1;
  *(uint2*)dst = u;
}

// ---------------- router: fp64 logits + softmax, build sort keys ----------------
__global__ __launch_bounds__(256)
void router_kernel(const float* __restrict__ x, const float* __restrict__ rw,
                   float* __restrict__ logits_out, float* __restrict__ probs_ws,
                   unsigned long long* __restrict__ keys_ws) {
  int t = blockIdx.x;
  int tid = threadIdx.x;
  int lane = tid & 63, wid = tid >> 6;
  __shared__ float xs[D_DIM];
  __shared__ double dred[4 * E_EXP];
  __shared__ double dlog[E_EXP];
  for (int i = tid; i < D_DIM; i += 256) xs[i] = x[(size_t)t * D_DIM + i];
  __syncthreads();
#pragma unroll
  for (int e = 0; e < E_EXP; e++) {
    double s = 0.0;
#pragma unroll
    for (int i = 0; i < 4; i++) {
      int d = tid + i * 256;
      s += (double)xs[d] * (double)rw[e * D_DIM + d];
    }
#pragma unroll
    for (int off = 32; off > 0; off >>= 1) s += __shfl_down(s, off, 64);
    if (lane == 0) dred[wid * E_EXP + e] = s;
  }
  __syncthreads();
  if (tid < E_EXP) {
    double s = dred[tid] + dred[E_EXP + tid] + dred[2 * E_EXP + tid] + dred[3 * E_EXP + tid];
    dlog[tid] = s;
    logits_out[(size_t)t * E_EXP + tid] = (float)s;
  }
  __syncthreads();
  if (tid == 0) {
    double m = dlog[0];
#pragma unroll
    for (int e = 1; e < E_EXP; e++) m = dlog[e] > m ? dlog[e] : m;
    double ex[E_EXP], Z = 0.0;
#pragma unroll
    for (int e = 0; e < E_EXP; e++) { ex[e] = exp(dlog[e] - m); Z += ex[e]; }
#pragma unroll
    for (int e = 0; e < E_EXP; e++) {
      double p = ex[e] / Z;
      probs_ws[e * T_TOK + t] = (float)p;
      unsigned long long b = (unsigned long long)__double_as_longlong(p);
      keys_ws[e * T_TOK + t] = (b & ~8191ULL) | (unsigned long long)(8191 - t);
    }
  }
}

// ---------------- exact top-k by rank counting (256 blocks) ----------------
__global__ __launch_bounds__(256)
void topk_kernel(const unsigned long long* __restrict__ keys_ws,
                 const float* __restrict__ probs_ws,
                 int* __restrict__ sel_ws, float* __restrict__ wt_ws,
                 float* __restrict__ selout) {
  int e = blockIdx.x >> 5, seg = blockIdx.x & 31;
  int tid = threadIdx.x;
  const unsigned long long* keys = keys_ws + (size_t)e * T_TOK;
  __shared__ unsigned long long kbuf[2048];
  int t = seg * 256 + tid;
  unsigned long long own = keys[t];
  int rank = 0;
  for (int pass = 0; pass < 4; pass++) {
    __syncthreads();
    for (int j = tid; j < 2048; j += 256) kbuf[j] = keys[pass * 2048 + j];
    __syncthreads();
#pragma unroll 8
    for (int j = 0; j < 2048; j++) rank += (kbuf[j] > own);
  }
  if (rank < K_CAP) {
    sel_ws[e * K_CAP + rank] = t;
    wt_ws[e * K_CAP + rank] = probs_ws[e * T_TOK + t];
    selout[e * K_CAP + rank] = (float)t;
  }
}

// ---------------- m97-style bf16 MFMA GEMM ----------------
// C[128,128] tile; A rows bf16 (MODE1: gathered x_bf; MODE2: h rows),
// B^T bf16 [NDIM][KDIM] rows. Unpadded LDS, global_load_lds staging.
template <int MODE, int KDIM, int NDIM>
__global__ __launch_bounds__(256, 2)
void gemm_kernel(const unsigned short* __restrict__ abase,
                 const unsigned short* __restrict__ bt,
                 const float* __restrict__ bias,
                 const int* __restrict__ sel,
                 const float* __restrict__ wt,
                 unsigned short* __restrict__ hout,
                 float* __restrict__ results) {
  int e = blockIdx.z;
  int n0 = blockIdx.x * 128;
  int m0 = blockIdx.y * 128;
  int tid = threadIdx.x;
  int lane = tid & 63, wid = tid >> 6;
  int wave_m = wid >> 1, wave_n = wid & 1;
  __shared__ unsigned short As[128 * 32];
  __shared__ unsigned short Bs[128 * 32];

  int r0 = tid >> 2;            // 0..63 (row within half-tile)
  int coff = (tid & 3) * 8;     // shorts within 32-short row slice
  const unsigned short* aptr0;
  const unsigned short* aptr1;
  if (MODE == 1) {
    aptr0 = abase + (size_t)sel[e * K_CAP + m0 + r0] * KDIM + coff;
    aptr1 = abase + (size_t)sel[e * K_CAP + m0 + 64 + r0] * KDIM + coff;
  } else {
    aptr0 = abase + ((size_t)e * K_CAP + m0 + r0) * KDIM + coff;
    aptr1 = aptr0 + (size_t)64 * KDIM;
  }
  const unsigned short* bptr0 = bt + ((size_t)e * NDIM + n0 + r0) * KDIM + coff;
  const unsigned short* bptr1 = bptr0 + (size_t)64 * KDIM;

  char* ldsA0 = (char*)As + wid * 1024;
  char* ldsA1 = ldsA0 + 4096;
  char* ldsB0 = (char*)Bs + wid * 1024;
  char* ldsB1 = ldsB0 + 4096;

  floatx4 acc[4][4];
#pragma unroll
  for (int i = 0; i < 4; i++)
#pragma unroll
    for (int j = 0; j < 4; j++) acc[i][j] = (floatx4)0.0f;

  int lm = lane & 15;
  int q8 = (lane >> 4) * 8;

  for (int k0 = 0; k0 < KDIM; k0 += 32) {
    ASYNC_CP16(aptr0, ldsA0);
    ASYNC_CP16(aptr1, ldsA1);
    ASYNC_CP16(bptr0, ldsB0);
    ASYNC_CP16(bptr1, ldsB1);
    aptr0 += 32; aptr1 += 32; bptr0 += 32; bptr1 += 32;
    __syncthreads();
    short8 av[4], bv[4];
#pragma unroll
    for (int i = 0; i < 4; i++) {
      av[i] = *(const short8*)&As[(wave_m * 64 + i * 16 + lm) * 32 + q8];
      bv[i] = *(const short8*)&Bs[(wave_n * 64 + i * 16 + lm) * 32 + q8];
    }
#pragma unroll
    for (int mi = 0; mi < 4; mi++)
#pragma unroll
      for (int ni = 0; ni < 4; ni++)
        acc[mi][ni] = __builtin_amdgcn_mfma_f32_16x16x32_bf16(av[mi], bv[ni], acc[mi][ni], 0, 0, 0);
    __syncthreads();
  }

  // ---- epilogue ----
  int quad = lane >> 4;
  float bs[4];
#pragma unroll
  for (int ni = 0; ni < 4; ni++)
    bs[ni] = bias[e * NDIM + n0 + wave_n * 64 + ni * 16 + lm];
#pragma unroll
  for (int mi = 0; mi < 4; mi++) {
#pragma unroll
    for (int rg = 0; rg < 4; rg++) {
      int m_l = wave_m * 64 + mi * 16 + quad * 4 + rg;
      int m_g = m0 + m_l;
      if (MODE == 1) {
#pragma unroll
        for (int ni = 0; ni < 4; ni++) {
          int n_l = wave_n * 64 + ni * 16 + lm;
          float v = acc[mi][ni][rg] + bs[ni];
          float gl = 0.5f * v * (1.0f + erff(v * 0.70710678118f));  // exact GELU
          hout[((size_t)e * K_CAP + m_g) * H_DIM + n0 + n_l] = (unsigned short)f2bf_u(gl);
        }
      } else {
        int tok = sel[e * K_CAP + m_g];
        float wgt = wt[e * K_CAP + m_g];
#pragma unroll
        for (int ni = 0; ni < 4; ni++) {
          int n_l = wave_n * 64 + ni * 16 + lm;
          float v = (acc[mi][ni][rg] + bs[ni]) * wgt;
          atomicAdd(&results[(size_t)tok * D_DIM + n0 + n_l], v);
        }
      }
    }
  }
}

extern "C" void kernel_launch(void* const* d_in, const int* in_sizes, int n_in,
                              void* d_out, int out_size, void* d_ws, size_t ws_size,
                              hipStream_t stream) {
  const float* x  = (const float*)d_in[0];
  const float* rw = (const float*)d_in[1];
  const float* w1 = (const float*)d_in[2];
  const float* b1 = (const float*)d_in[3];
  const float* w2 = (const float*)d_in[4];
  const float* b2 = (const float*)d_in[5];

  float* out_res = (float*)d_out;                      // [8192][1024] fp32
  float* out_log = out_res + (size_t)T_TOK * D_DIM;    // [8192][8] fp32
  float* out_sel = out_log + (size_t)T_TOK * E_EXP;    // [8][1024] token ids as float

  char* ws = (char*)d_ws;
  float* probs_ws = (float*)ws;                                      // 256KB
  unsigned long long* keys_ws = (unsigned long long*)(ws + 262144);  // 512KB
  int* sel_ws = (int*)(ws + 786432);                                 // 32KB
  float* wt_ws = (float*)(ws + 819200);                              // 32KB
  unsigned short* x_bf = (unsigned short*)(ws + 1048576);            // 16MB
  unsigned short* h_ws = (unsigned short*)(ws + 17825792);           // 64MB
  unsigned short* t_buf = (unsigned short*)(ws + 84934656);          // 64MB (w1t, then w2t)

  zero_kernel<<<(T_TOK * D_DIM / 4 + 255) / 256, 256, 0, stream>>>(out_res, T_TOK * D_DIM / 4);

  convert_kernel<<<(T_TOK * D_DIM / 4 + 255) / 256, 256, 0, stream>>>(
      x, x_bf, T_TOK * D_DIM / 4);

  router_kernel<<<T_TOK, 256, 0, stream>>>(x, rw, out_log, probs_ws, keys_ws);

  topk_kernel<<<256, 256, 0, stream>>>(keys_ws, probs_ws, sel_ws, wt_ws, out_sel);

  // w1 [E][D][H] -> w1t [E][H][D] bf16
  transpose_kernel<D_DIM, H_DIM><<<dim3(H_DIM / 32, D_DIM / 32, E_EXP), 256, 0, stream>>>(
      w1, t_buf);

  // H = gelu(Xg @ W1 + b1) -> bf16
  gemm_kernel<1, D_DIM, H_DIM><<<dim3(H_DIM / 128, K_CAP / 128, E_EXP), 256, 0, stream>>>(
      x_bf, t_buf, b1, sel_ws, wt_ws, h_ws, nullptr);

  // w2 [E][H][D] -> w2t [E][D][H] bf16 (reuse t_buf)
  transpose_kernel<H_DIM, D_DIM><<<dim3(D_DIM / 32, H_DIM / 32, E_EXP), 256, 0, stream>>>(
      w2, t_buf);

  // results += weight * (H @ W2 + b2), scattered by token
  gemm_kernel<2, H_DIM, D_DIM><<<dim3(D_DIM / 128, K_CAP / 128, E_EXP), 256, 0, stream>>>(
      h_ws, t_buf, b2, sel_ws, wt_ws, nullptr, out_res);
}